// Round 1
// baseline (685.853 us; speedup 1.0000x reference)
//
#include <hip/hip_runtime.h>

// Problem constants (from reference)
#define N_NODES 50000
#define N_EDGES 800000
#define NG      128
#define FIN     64
#define HD      108
#define NB      8     // nodes per block in GEMM passes (50000 % 8 == 0)

// ---------------------------------------------------------------------------
// CSR construction: count, scan, fill
// ---------------------------------------------------------------------------
__global__ void count_k(const int* __restrict__ dst, int* __restrict__ deg,
                        int* __restrict__ pos) {
    int e = blockIdx.x * 256 + threadIdx.x;
    if (e < N_EDGES) pos[e] = atomicAdd(&deg[dst[e]], 1);
}

// single-block exclusive scan over deg[N_NODES] -> row_ptr[N_NODES+1]
__global__ void scan_k(const int* __restrict__ deg, int* __restrict__ row_ptr) {
    __shared__ int s_wsum[16];
    __shared__ int s_carry;
    int t = threadIdx.x;            // 1024 threads = 16 waves
    int lane = t & 63, wid = t >> 6;
    if (t == 0) s_carry = 0;
    __syncthreads();
    for (int base = 0; base < N_NODES; base += 1024) {
        int i = base + t;
        int v = (i < N_NODES) ? deg[i] : 0;
        int x = v;
        #pragma unroll
        for (int off = 1; off < 64; off <<= 1) {
            int y = __shfl_up(x, off);
            if (lane >= off) x += y;
        }
        if (lane == 63) s_wsum[wid] = x;
        __syncthreads();
        if (wid == 0 && lane < 16) {
            int y = s_wsum[lane];
            #pragma unroll
            for (int off = 1; off < 16; off <<= 1) {
                int z = __shfl_up(y, off);
                if (lane >= off) y += z;
            }
            s_wsum[lane] = y;
        }
        __syncthreads();
        int waveoff = (wid == 0) ? 0 : s_wsum[wid - 1];
        int carry = s_carry;
        if (i < N_NODES) row_ptr[i] = carry + waveoff + x - v;   // exclusive
        __syncthreads();
        if (t == 1023) s_carry = carry + s_wsum[15];
        __syncthreads();
    }
    if (t == 0) row_ptr[N_NODES] = s_carry;
}

__global__ void fill_k(const int* __restrict__ src, const int* __restrict__ dst,
                       const int* __restrict__ row_ptr, const int* __restrict__ pos,
                       int* __restrict__ csr) {
    int e = blockIdx.x * 256 + threadIdx.x;
    if (e < N_EDGES) csr[row_ptr[dst[e]] + pos[e]] = src[e];
}

__global__ void gcount_k(const int* __restrict__ gids, int* __restrict__ gcnt) {
    int n = blockIdx.x * 256 + threadIdx.x;
    if (n < N_NODES) atomicAdd(&gcnt[gids[n]], 1);
}

// ---------------------------------------------------------------------------
// Pass A: h = feat @ Wemb + bemb ; m = relu(h @ Wp1 + bp1)     (per node)
// ---------------------------------------------------------------------------
__global__ void embed_pool_k(const float* __restrict__ feat,
                             const float* __restrict__ Wemb, const float* __restrict__ bemb,
                             const float* __restrict__ Wp,   const float* __restrict__ bp,
                             float* __restrict__ h, float* __restrict__ m) {
    __shared__ float s_in[NB][FIN];
    __shared__ float s_h[NB][HD];
    int t = threadIdx.x;
    int v0 = blockIdx.x * NB;
    for (int idx = t; idx < NB * FIN; idx += 128) {
        int i = idx >> 6, k = idx & 63;
        s_in[i][k] = feat[(v0 + i) * FIN + k];
    }
    __syncthreads();
    if (t < HD) {
        float acc[NB];
        #pragma unroll
        for (int i = 0; i < NB; i++) acc[i] = bemb[t];
        for (int k = 0; k < FIN; k++) {
            float w = Wemb[k * HD + t];
            #pragma unroll
            for (int i = 0; i < NB; i++) acc[i] = fmaf(s_in[i][k], w, acc[i]);
        }
        #pragma unroll
        for (int i = 0; i < NB; i++) {
            h[(v0 + i) * HD + t] = acc[i];
            s_h[i][t] = acc[i];
        }
    }
    __syncthreads();
    if (t < HD) {
        float acc[NB];
        #pragma unroll
        for (int i = 0; i < NB; i++) acc[i] = bp[t];
        for (int k = 0; k < HD; k++) {
            float w = Wp[k * HD + t];
            #pragma unroll
            for (int i = 0; i < NB; i++) acc[i] = fmaf(s_h[i][k], w, acc[i]);
        }
        #pragma unroll
        for (int i = 0; i < NB; i++) m[(v0 + i) * HD + t] = fmaxf(acc[i], 0.0f);
    }
}

// ---------------------------------------------------------------------------
// Aggregation: c[v] = mean over incoming edges of m[src]      (atomic-free)
// ---------------------------------------------------------------------------
__global__ void aggregate_k(const float* __restrict__ m, const int* __restrict__ row_ptr,
                            const int* __restrict__ csr, float* __restrict__ c) {
    int v = blockIdx.x, t = threadIdx.x;
    int beg = row_ptr[v], end = row_ptr[v + 1];
    float s = 0.0f;
    for (int i = beg; i < end; ++i) {
        int sv = csr[i];                       // wave-uniform -> scalar load
        if (t < HD) s += m[sv * HD + t];
    }
    if (t < HD) {
        int d = end - beg;
        float inv = (d > 0) ? 1.0f / (float)d : 0.0f;
        c[v * HD + t] = s * inv;
    }
}

// ---------------------------------------------------------------------------
// Pass C/E: bundle = [h,c] @ Wn + bn ; L2-normalize ; h' = h + relu(.)
//  FINAL=false: write h in place + m2 = relu(h' @ Wp2 + bp2)
//  FINAL=true : accumulate h' into per-graph sums
// ---------------------------------------------------------------------------
template <bool FINAL>
__global__ void apply_k(const float* __restrict__ h, const float* __restrict__ c,
                        const float* __restrict__ Wn, const float* __restrict__ bn,
                        const float* __restrict__ Wp, const float* __restrict__ bp,
                        float* __restrict__ hout, float* __restrict__ mout,
                        const int* __restrict__ gids, float* __restrict__ gsum) {
    __shared__ float s_h[NB][HD];
    __shared__ float s_c[NB][HD];
    __shared__ float s_b[NB][HD];
    __shared__ float s_rn[NB];
    __shared__ int   s_g[NB];
    int t = threadIdx.x;
    int v0 = blockIdx.x * NB;

    for (int idx = t; idx < NB * HD; idx += 128) {
        int i = idx / HD, k = idx - i * HD;
        s_h[i][k] = h[(v0 + i) * HD + k];
        s_c[i][k] = c[(v0 + i) * HD + k];
    }
    if (FINAL && t < NB) s_g[t] = gids[v0 + t];
    __syncthreads();

    if (t < HD) {
        float acc[NB];
        #pragma unroll
        for (int i = 0; i < NB; i++) acc[i] = bn[t];
        for (int k = 0; k < HD; k++) {
            float w = Wn[k * HD + t];
            #pragma unroll
            for (int i = 0; i < NB; i++) acc[i] = fmaf(s_h[i][k], w, acc[i]);
        }
        for (int k = 0; k < HD; k++) {
            float w = Wn[(HD + k) * HD + t];
            #pragma unroll
            for (int i = 0; i < NB; i++) acc[i] = fmaf(s_c[i][k], w, acc[i]);
        }
        #pragma unroll
        for (int i = 0; i < NB; i++) s_b[i][t] = acc[i];
    }
    __syncthreads();

    if (t < NB) {
        float s = 0.0f;
        for (int k = 0; k < HD; k++) { float x = s_b[t][k]; s = fmaf(x, x, s); }
        s_rn[t] = 1.0f / fmaxf(sqrtf(s), 1e-12f);
    }
    __syncthreads();

    float hn[NB];
    if (t < HD) {
        #pragma unroll
        for (int i = 0; i < NB; i++) {
            hn[i] = s_h[i][t] + fmaxf(s_b[i][t] * s_rn[i], 0.0f);
            s_h[i][t] = hn[i];
        }
        if (!FINAL) {
            #pragma unroll
            for (int i = 0; i < NB; i++) hout[(v0 + i) * HD + t] = hn[i];
        }
    }
    __syncthreads();

    if (!FINAL) {
        if (t < HD) {
            float acc[NB];
            #pragma unroll
            for (int i = 0; i < NB; i++) acc[i] = bp[t];
            for (int k = 0; k < HD; k++) {
                float w = Wp[k * HD + t];
                #pragma unroll
                for (int i = 0; i < NB; i++) acc[i] = fmaf(s_h[i][k], w, acc[i]);
            }
            #pragma unroll
            for (int i = 0; i < NB; i++) mout[(v0 + i) * HD + t] = fmaxf(acc[i], 0.0f);
        }
    } else {
        if (t < HD) {
            int g0 = s_g[0];
            bool uni = (g0 == s_g[NB - 1]);   // graph_ids sorted
            if (uni) {
                float s = 0.0f;
                #pragma unroll
                for (int i = 0; i < NB; i++) s += hn[i];
                atomicAdd(&gsum[g0 * HD + t], s);
            } else {
                #pragma unroll
                for (int i = 0; i < NB; i++) atomicAdd(&gsum[s_g[i] * HD + t], hn[i]);
            }
        }
    }
}

__global__ void finalize_k(const float* __restrict__ gsum, const int* __restrict__ gcnt,
                           float* __restrict__ out) {
    int i = blockIdx.x * 256 + threadIdx.x;
    if (i < NG * HD) {
        int g = i / HD;
        int cnt = gcnt[g];
        float inv = (cnt > 0) ? 1.0f / (float)cnt : 0.0f;
        out[i] = gsum[i] * inv;
    }
}

// ---------------------------------------------------------------------------
extern "C" void kernel_launch(void* const* d_in, const int* in_sizes, int n_in,
                              void* d_out, int out_size, void* d_ws, size_t ws_size,
                              hipStream_t stream) {
    const float* feat = (const float*)d_in[0];
    // d_in[1..3] (edges_feat, nodes_num_norm_sqrt, edges_num_norm_sqrt) unused by reference
    const int* src  = (const int*)d_in[4];
    const int* dst  = (const int*)d_in[5];
    const int* gids = (const int*)d_in[6];
    const float* Wemb = (const float*)d_in[7];
    const float* bemb = (const float*)d_in[8];
    const float* Wp1  = (const float*)d_in[9];
    const float* bp1  = (const float*)d_in[10];
    const float* Wn1  = (const float*)d_in[11];
    const float* bn1  = (const float*)d_in[12];
    const float* Wp2  = (const float*)d_in[13];
    const float* bp2  = (const float*)d_in[14];
    const float* Wn2  = (const float*)d_in[15];
    const float* bn2  = (const float*)d_in[16];
    float* out = (float*)d_out;

    char* ws = (char*)d_ws;
    size_t off = 0;
    auto carve = [&](size_t bytes) -> char* {
        char* p = ws + off;
        off = (off + bytes + 255) & ~(size_t)255;
        return p;
    };
    float* h      = (float*)carve((size_t)N_NODES * HD * 4);
    float* m      = (float*)carve((size_t)N_NODES * HD * 4);
    float* cbuf   = (float*)carve((size_t)N_NODES * HD * 4);
    int*   deg    = (int*)  carve((size_t)N_NODES * 4);
    int*   rowp   = (int*)  carve((size_t)(N_NODES + 1) * 4);
    int*   pos    = (int*)  carve((size_t)N_EDGES * 4);
    int*   csr    = (int*)  carve((size_t)N_EDGES * 4);
    float* gsum   = (float*)carve((size_t)NG * HD * 4);
    int*   gcnt   = (int*)  carve((size_t)NG * 4);
    (void)ws_size; (void)in_sizes; (void)n_in; (void)out_size;

    hipMemsetAsync(deg,  0, (size_t)N_NODES * 4, stream);
    hipMemsetAsync(gsum, 0, (size_t)NG * HD * 4, stream);
    hipMemsetAsync(gcnt, 0, (size_t)NG * 4, stream);

    count_k<<<(N_EDGES + 255) / 256, 256, 0, stream>>>(dst, deg, pos);
    scan_k<<<1, 1024, 0, stream>>>(deg, rowp);
    fill_k<<<(N_EDGES + 255) / 256, 256, 0, stream>>>(src, dst, rowp, pos, csr);
    gcount_k<<<(N_NODES + 255) / 256, 256, 0, stream>>>(gids, gcnt);

    embed_pool_k<<<N_NODES / NB, 128, 0, stream>>>(feat, Wemb, bemb, Wp1, bp1, h, m);

    aggregate_k<<<N_NODES, 128, 0, stream>>>(m, rowp, csr, cbuf);
    apply_k<false><<<N_NODES / NB, 128, 0, stream>>>(h, cbuf, Wn1, bn1, Wp2, bp2,
                                                     h, m, nullptr, nullptr);

    aggregate_k<<<N_NODES, 128, 0, stream>>>(m, rowp, csr, cbuf);
    apply_k<true><<<N_NODES / NB, 128, 0, stream>>>(h, cbuf, Wn2, bn2, nullptr, nullptr,
                                                    nullptr, nullptr, gids, gsum);

    finalize_k<<<(NG * HD + 255) / 256, 256, 0, stream>>>(gsum, gcnt, out);
}

// Round 2
// 335.096 us; speedup vs baseline: 2.0467x; 2.0467x over previous
//
#include <hip/hip_runtime.h>

#define N_NODES 50000
#define N_EDGES 800000
#define NG      128
#define FIN     64
#define HD      108
#define SCAN_B  49          // ceil(50000/1024)

typedef __attribute__((ext_vector_type(8))) short s16x8;   // 8 bf16 = 4 VGPRs
typedef __attribute__((ext_vector_type(4))) float f32x4;

__device__ __forceinline__ unsigned short bf16_rne(float x) {
    unsigned u = __float_as_uint(x);
    u += 0x7FFFu + ((u >> 16) & 1u);
    return (unsigned short)(u >> 16);
}
__device__ __forceinline__ float bf16_to_f(unsigned u16) {
    return __uint_as_float(u16 << 16);
}

// ---------------------------------------------------------------------------
// CSR construction
// ---------------------------------------------------------------------------
__global__ void count_k(const int* __restrict__ dst, int* __restrict__ deg,
                        int* __restrict__ pos) {
    int e = blockIdx.x * 256 + threadIdx.x;
    if (e < N_EDGES) pos[e] = atomicAdd(&deg[dst[e]], 1);
}

// per-1024-chunk exclusive scan, block sums out
__global__ void scan1_k(const int* __restrict__ deg, int* __restrict__ rowp,
                        int* __restrict__ bsum) {
    __shared__ int s_w[16];
    int t = threadIdx.x, lane = t & 63, wid = t >> 6;
    int i = blockIdx.x * 1024 + t;
    int v = (i < N_NODES) ? deg[i] : 0;
    int x = v;
    #pragma unroll
    for (int off = 1; off < 64; off <<= 1) {
        int y = __shfl_up(x, off);
        if (lane >= off) x += y;
    }
    if (lane == 63) s_w[wid] = x;
    __syncthreads();
    if (t < 16) {
        int y = s_w[t];
        #pragma unroll
        for (int off = 1; off < 16; off <<= 1) {
            int z = __shfl_up(y, off);
            if (t >= off) y += z;
        }
        s_w[t] = y;
    }
    __syncthreads();
    int woff = wid ? s_w[wid - 1] : 0;
    if (i < N_NODES) rowp[i] = woff + x - v;         // exclusive within chunk
    if (t == 1023) bsum[blockIdx.x] = s_w[15];
}

__global__ void scan2_k(const int* __restrict__ bsum, int* __restrict__ boff,
                        int* __restrict__ rowp) {
    int t = threadIdx.x;                              // 64 threads
    int v = (t < SCAN_B) ? bsum[t] : 0;
    int x = v;
    #pragma unroll
    for (int off = 1; off < 64; off <<= 1) {
        int y = __shfl_up(x, off);
        if (t >= off) x += y;
    }
    if (t < SCAN_B) boff[t] = x - v;                  // exclusive
    if (t == SCAN_B - 1) rowp[N_NODES] = x;           // total = E
}

__global__ void scan3_k(int* __restrict__ rowp, const int* __restrict__ boff) {
    int i = blockIdx.x * 1024 + threadIdx.x;
    if (i < N_NODES) rowp[i] += boff[blockIdx.x];
}

__global__ void fill_k(const int* __restrict__ src, const int* __restrict__ dst,
                       const int* __restrict__ rowp, const int* __restrict__ pos,
                       int* __restrict__ csr) {
    int e = blockIdx.x * 256 + threadIdx.x;
    if (e < N_EDGES) csr[rowp[dst[e]] + pos[e]] = src[e];
}

__global__ void gcount_k(const int* __restrict__ gids, int* __restrict__ gcnt) {
    int n = blockIdx.x * 256 + threadIdx.x;
    if (n < N_NODES) atomicAdd(&gcnt[gids[n]], 1);
}

// ---------------------------------------------------------------------------
// Prep: feat f32 -> bf16 ; zero hc pad cols ; weights -> MFMA fragment order
// ---------------------------------------------------------------------------
__global__ void fconv_k(const float* __restrict__ in, unsigned short* __restrict__ out) {
    int i = blockIdx.x * 256 + threadIdx.x;           // one thread = 8 elems
    if (i >= N_NODES * FIN / 8) return;
    const float4* p = (const float4*)(in + (size_t)i * 8);
    float4 a = p[0], b = p[1];
    s16x8 o;
    o[0] = (short)bf16_rne(a.x); o[1] = (short)bf16_rne(a.y);
    o[2] = (short)bf16_rne(a.z); o[3] = (short)bf16_rne(a.w);
    o[4] = (short)bf16_rne(b.x); o[5] = (short)bf16_rne(b.y);
    o[6] = (short)bf16_rne(b.z); o[7] = (short)bf16_rne(b.w);
    *(s16x8*)(out + (size_t)i * 8) = o;
}

__global__ void zeropad_k(unsigned short* __restrict__ hc) {
    int i = blockIdx.x * 256 + threadIdx.x;
    if (i < N_NODES) {
        s16x8 z = {0, 0, 0, 0, 0, 0, 0, 0};
        *(s16x8*)(hc + (size_t)i * 224 + 216) = z;    // cols 216..223 = 0
    }
}

// fragment-order weights: for ks-tile, n-tile: lane l elem j =
//   W[ks*32 + (l>>4)*8 + j][nt*16 + (l&15)]  (0 outside real K x 108)
// kstile layout (global): Wemb ks 0..1, Wp1 2..5, Wn1 6..12, Wp2 13..16, Wn2 17..23
__global__ void wprep_k(const float* __restrict__ W0, const float* __restrict__ W1,
                        const float* __restrict__ W2, const float* __restrict__ W3,
                        const float* __restrict__ W4, unsigned short* __restrict__ Wf) {
    int b = blockIdx.x;                               // 0..167 = kst*7 + nt
    int kst = b / 7, nt = b % 7, lane = threadIdx.x;  // 64 threads
    const float* W; int Kr, ks;
    if (kst < 2)       { W = W0; Kr = 64;  ks = kst;      }
    else if (kst < 6)  { W = W1; Kr = 108; ks = kst - 2;  }
    else if (kst < 13) { W = W2; Kr = 216; ks = kst - 6;  }
    else if (kst < 17) { W = W3; Kr = 108; ks = kst - 13; }
    else               { W = W4; Kr = 216; ks = kst - 17; }
    int n = nt * 16 + (lane & 15);
    s16x8 o;
    #pragma unroll
    for (int j = 0; j < 8; ++j) {
        int k = ks * 32 + (lane >> 4) * 8 + j;
        float v = (k < Kr && n < HD) ? W[k * HD + n] : 0.0f;
        o[j] = (short)bf16_rne(v);
    }
    *(s16x8*)(Wf + (size_t)b * 512 + lane * 8) = o;
}

// ---------------------------------------------------------------------------
// MFMA GEMM: one wave = 16 nodes x 112 out-cols (7 tiles), K = KSTEPS*32
// EPI: 0=embed(h f32 + hc bf16)  1=pool(relu -> m bf16)
//      2=apply(norm+residual -> h f32 + hc bf16)  3=apply-final(-> gsum atomics)
// ---------------------------------------------------------------------------
template <int KSTEPS, int EPI>
__global__ __launch_bounds__(256) void gemm_k(
    const unsigned short* __restrict__ A, int strideA,
    const unsigned short* __restrict__ Wf, const float* __restrict__ bias,
    float* __restrict__ hio, unsigned short* __restrict__ obf, int strideO,
    const int* __restrict__ gids, float* __restrict__ gsum) {
    int t = threadIdx.x, lane = t & 63, wave = t >> 6;
    int wrow = (blockIdx.x * 4 + wave) * 16;
    if (wrow >= N_NODES) return;
    int l15 = lane & 15, lg = lane >> 4;

    f32x4 acc[7];
    #pragma unroll
    for (int nt = 0; nt < 7; ++nt) acc[nt] = (f32x4){0.f, 0.f, 0.f, 0.f};

    const unsigned short* arow = A + (size_t)(wrow + l15) * strideA + lg * 8;
    #pragma unroll
    for (int ks = 0; ks < KSTEPS; ++ks) {
        s16x8 a = *(const s16x8*)(arow + ks * 32);
        const unsigned short* wp = Wf + ((size_t)(ks * 7) * 64 + lane) * 8;
        #pragma unroll
        for (int nt = 0; nt < 7; ++nt) {
            s16x8 b = *(const s16x8*)(wp + (size_t)nt * 512);
            acc[nt] = __builtin_amdgcn_mfma_f32_16x16x32_bf16(a, b, acc[nt], 0, 0, 0);
        }
    }

    // D layout: col = nt*16 + l15, row = wrow + lg*4 + r
    if (EPI == 0) {                                   // embed
        #pragma unroll
        for (int nt = 0; nt < 7; ++nt) {
            int col = nt * 16 + l15;
            if (col >= HD) continue;
            float bv = bias[col];
            #pragma unroll
            for (int r = 0; r < 4; ++r) {
                int row = wrow + lg * 4 + r;
                float v = acc[nt][r] + bv;
                hio[(size_t)row * HD + col] = v;
                obf[(size_t)row * 224 + col] = bf16_rne(v);
            }
        }
    } else if (EPI == 1) {                            // pool: relu -> m bf16
        #pragma unroll
        for (int nt = 0; nt < 7; ++nt) {
            int col = nt * 16 + l15;
            float bv = (col < HD) ? bias[col] : 0.0f;
            #pragma unroll
            for (int r = 0; r < 4; ++r) {
                int row = wrow + lg * 4 + r;
                float v = fmaxf(acc[nt][r] + bv, 0.0f);
                obf[(size_t)row * strideO + col] = bf16_rne(v);
            }
        }
    } else {                                          // apply / apply-final
        float bval[7][4];
        float ss[4] = {0.f, 0.f, 0.f, 0.f};
        #pragma unroll
        for (int nt = 0; nt < 7; ++nt) {
            int col = nt * 16 + l15;
            bool valid = (col < HD);
            float bv = valid ? bias[col] : 0.0f;
            #pragma unroll
            for (int r = 0; r < 4; ++r) {
                float v = valid ? (acc[nt][r] + bv) : 0.0f;
                bval[nt][r] = v;
                ss[r] += v * v;
            }
        }
        #pragma unroll
        for (int r = 0; r < 4; ++r) {
            ss[r] += __shfl_xor(ss[r], 1);
            ss[r] += __shfl_xor(ss[r], 2);
            ss[r] += __shfl_xor(ss[r], 4);
            ss[r] += __shfl_xor(ss[r], 8);
        }
        float rn[4];
        #pragma unroll
        for (int r = 0; r < 4; ++r) rn[r] = 1.0f / fmaxf(sqrtf(ss[r]), 1e-12f);

        float hn[7][4];
        #pragma unroll
        for (int nt = 0; nt < 7; ++nt) {
            int col = nt * 16 + l15;
            bool valid = (col < HD);
            #pragma unroll
            for (int r = 0; r < 4; ++r) {
                int row = wrow + lg * 4 + r;
                float hv = valid ? hio[(size_t)row * HD + col] : 0.0f;
                hn[nt][r] = hv + fmaxf(bval[nt][r] * rn[r], 0.0f);
            }
        }
        if (EPI == 2) {
            #pragma unroll
            for (int nt = 0; nt < 7; ++nt) {
                int col = nt * 16 + l15;
                if (col >= HD) continue;
                #pragma unroll
                for (int r = 0; r < 4; ++r) {
                    int row = wrow + lg * 4 + r;
                    hio[(size_t)row * HD + col] = hn[nt][r];
                    obf[(size_t)row * 224 + col] = bf16_rne(hn[nt][r]);
                }
            }
        } else {                                      // EPI == 3: graph-mean accum
            int g0 = gids[wrow], g15 = gids[wrow + 15];
            if (g0 == g15) {
                #pragma unroll
                for (int nt = 0; nt < 7; ++nt) {
                    int col = nt * 16 + l15;
                    float cs = hn[nt][0] + hn[nt][1] + hn[nt][2] + hn[nt][3];
                    cs += __shfl_xor(cs, 16);
                    cs += __shfl_xor(cs, 32);
                    if (lane < 16 && col < HD) atomicAdd(&gsum[g0 * HD + col], cs);
                }
            } else {
                int gr[4];
                #pragma unroll
                for (int r = 0; r < 4; ++r) gr[r] = gids[wrow + lg * 4 + r];
                #pragma unroll
                for (int nt = 0; nt < 7; ++nt) {
                    int col = nt * 16 + l15;
                    if (col >= HD) continue;
                    #pragma unroll
                    for (int r = 0; r < 4; ++r)
                        atomicAdd(&gsum[gr[r] * HD + col], hn[nt][r]);
                }
            }
        }
    }
}

// ---------------------------------------------------------------------------
// Aggregation: c[v] = mean over incoming edges of m_bf[src]; write bf16
// into hc cols 108..215. One wave per node, lanes 0..53 own 2 cols each.
// ---------------------------------------------------------------------------
__global__ void aggregate_k(const unsigned short* __restrict__ m,
                            const int* __restrict__ rowp, const int* __restrict__ csr,
                            unsigned short* __restrict__ hc) {
    int v = blockIdx.x, t = threadIdx.x;
    int beg = rowp[v], end = rowp[v + 1];
    float s0 = 0.f, s1 = 0.f;
    if (t < 54) {
        int i = beg;
        for (; i + 1 < end; i += 2) {
            int sv0 = csr[i], sv1 = csr[i + 1];
            unsigned u0 = *(const unsigned*)(m + (size_t)sv0 * 112 + 2 * t);
            unsigned u1 = *(const unsigned*)(m + (size_t)sv1 * 112 + 2 * t);
            s0 += bf16_to_f(u0 & 0xFFFFu) + bf16_to_f(u1 & 0xFFFFu);
            s1 += bf16_to_f(u0 >> 16) + bf16_to_f(u1 >> 16);
        }
        if (i < end) {
            int sv = csr[i];
            unsigned u = *(const unsigned*)(m + (size_t)sv * 112 + 2 * t);
            s0 += bf16_to_f(u & 0xFFFFu);
            s1 += bf16_to_f(u >> 16);
        }
        float inv = (end > beg) ? 1.0f / (float)(end - beg) : 0.0f;
        unsigned pk = (unsigned)bf16_rne(s0 * inv) | ((unsigned)bf16_rne(s1 * inv) << 16);
        *(unsigned*)(hc + (size_t)v * 224 + 108 + 2 * t) = pk;
    }
}

__global__ void finalize_k(const float* __restrict__ gsum, const int* __restrict__ gcnt,
                           float* __restrict__ out) {
    int i = blockIdx.x * 256 + threadIdx.x;
    if (i < NG * HD) {
        int g = i / HD;
        int cnt = gcnt[g];
        float inv = (cnt > 0) ? 1.0f / (float)cnt : 0.0f;
        out[i] = gsum[i] * inv;
    }
}

// ---------------------------------------------------------------------------
extern "C" void kernel_launch(void* const* d_in, const int* in_sizes, int n_in,
                              void* d_out, int out_size, void* d_ws, size_t ws_size,
                              hipStream_t stream) {
    const float* feat = (const float*)d_in[0];
    const int* src  = (const int*)d_in[4];
    const int* dst  = (const int*)d_in[5];
    const int* gids = (const int*)d_in[6];
    const float* Wemb = (const float*)d_in[7];
    const float* bemb = (const float*)d_in[8];
    const float* Wp1  = (const float*)d_in[9];
    const float* bp1  = (const float*)d_in[10];
    const float* Wn1  = (const float*)d_in[11];
    const float* bn1  = (const float*)d_in[12];
    const float* Wp2  = (const float*)d_in[13];
    const float* bp2  = (const float*)d_in[14];
    const float* Wn2  = (const float*)d_in[15];
    const float* bn2  = (const float*)d_in[16];
    float* out = (float*)d_out;
    (void)in_sizes; (void)n_in; (void)out_size; (void)ws_size;

    char* ws = (char*)d_ws;
    size_t off = 0;
    auto carve = [&](size_t bytes) -> char* {
        char* p = ws + off;
        off = (off + bytes + 255) & ~(size_t)255;
        return p;
    };
    float*          h_f32 = (float*)carve((size_t)N_NODES * HD * 4);
    unsigned short* hc    = (unsigned short*)carve((size_t)N_NODES * 224 * 2);
    unsigned short* m_bf  = (unsigned short*)carve((size_t)N_NODES * 112 * 2);
    unsigned short* fbf   = (unsigned short*)carve((size_t)N_NODES * FIN * 2);
    unsigned short* Wf    = (unsigned short*)carve((size_t)24 * 7 * 512 * 2);
    int* deg  = (int*)carve((size_t)N_NODES * 4);
    int* rowp = (int*)carve((size_t)(N_NODES + 1) * 4);
    int* pos  = (int*)carve((size_t)N_EDGES * 4);
    int* csr  = (int*)carve((size_t)N_EDGES * 4);
    int* bsum = (int*)carve((size_t)SCAN_B * 4);
    int* boff = (int*)carve((size_t)SCAN_B * 4);
    float* gsum = (float*)carve((size_t)NG * HD * 4);
    int*   gcnt = (int*)carve((size_t)NG * 4);

    hipMemsetAsync(deg,  0, (size_t)N_NODES * 4, stream);
    hipMemsetAsync(gsum, 0, (size_t)NG * HD * 4, stream);
    hipMemsetAsync(gcnt, 0, (size_t)NG * 4, stream);

    // CSR + graph counts
    count_k<<<(N_EDGES + 255) / 256, 256, 0, stream>>>(dst, deg, pos);
    scan1_k<<<SCAN_B, 1024, 0, stream>>>(deg, rowp, bsum);
    scan2_k<<<1, 64, 0, stream>>>(bsum, boff, rowp);
    scan3_k<<<SCAN_B, 1024, 0, stream>>>(rowp, boff);
    fill_k<<<(N_EDGES + 255) / 256, 256, 0, stream>>>(src, dst, rowp, pos, csr);
    gcount_k<<<(N_NODES + 255) / 256, 256, 0, stream>>>(gids, gcnt);

    // prep
    fconv_k<<<(N_NODES * FIN / 8 + 255) / 256, 256, 0, stream>>>(feat, fbf);
    zeropad_k<<<(N_NODES + 255) / 256, 256, 0, stream>>>(hc);
    wprep_k<<<168, 64, 0, stream>>>(Wemb, Wp1, Wn1, Wp2, Wn2, Wf);

    const int GB = (N_NODES / 16 + 3) / 4;           // 782 blocks, 4 waves each
    unsigned short* Wf_emb = Wf + (size_t)0  * 7 * 512;
    unsigned short* Wf_p1  = Wf + (size_t)2  * 7 * 512;
    unsigned short* Wf_n1  = Wf + (size_t)6  * 7 * 512;
    unsigned short* Wf_p2  = Wf + (size_t)13 * 7 * 512;
    unsigned short* Wf_n2  = Wf + (size_t)17 * 7 * 512;

    // layer 0: embed
    gemm_k<2, 0><<<GB, 256, 0, stream>>>(fbf, FIN, Wf_emb, bemb, h_f32, hc, 224, nullptr, nullptr);
    // layer 1
    gemm_k<4, 1><<<GB, 256, 0, stream>>>(hc, 224, Wf_p1, bp1, nullptr, m_bf, 112, nullptr, nullptr);
    aggregate_k<<<N_NODES, 64, 0, stream>>>(m_bf, rowp, csr, hc);
    gemm_k<7, 2><<<GB, 256, 0, stream>>>(hc, 224, Wf_n1, bn1, h_f32, hc, 224, nullptr, nullptr);
    // layer 2
    gemm_k<4, 1><<<GB, 256, 0, stream>>>(hc, 224, Wf_p2, bp2, nullptr, m_bf, 112, nullptr, nullptr);
    aggregate_k<<<N_NODES, 64, 0, stream>>>(m_bf, rowp, csr, hc);
    gemm_k<7, 3><<<GB, 256, 0, stream>>>(hc, 224, Wf_n2, bn2, h_f32, nullptr, 0, gids, gsum);

    finalize_k<<<(NG * HD + 255) / 256, 256, 0, stream>>>(gsum, gcnt, out);
}

// Round 3
// 225.803 us; speedup vs baseline: 3.0374x; 1.4840x over previous
//
#include <hip/hip_runtime.h>

#define N_NODES 50000
#define N_EDGES 800000
#define NG      128
#define FIN     64
#define HD      108
#define SCAN_B  49          // ceil(50000/1024)

typedef __attribute__((ext_vector_type(8))) short s16x8;   // 8 bf16 = 4 VGPRs
typedef __attribute__((ext_vector_type(4))) float f32x4;

__device__ __forceinline__ unsigned short bf16_rne(float x) {
    unsigned u = __float_as_uint(x);
    u += 0x7FFFu + ((u >> 16) & 1u);
    return (unsigned short)(u >> 16);
}
__device__ __forceinline__ float bf16_to_f(unsigned u16) {
    return __uint_as_float(u16 << 16);
}

// ---------------------------------------------------------------------------
// CSR construction
// ---------------------------------------------------------------------------
__global__ void count_k(const int* __restrict__ dst, int* __restrict__ deg,
                        int* __restrict__ pos) {
    int e = blockIdx.x * 256 + threadIdx.x;
    if (e < N_EDGES) pos[e] = atomicAdd(&deg[dst[e]], 1);
}

// per-1024-chunk exclusive scan, block sums out
__global__ void scan1_k(const int* __restrict__ deg, int* __restrict__ rowp,
                        int* __restrict__ bsum) {
    __shared__ int s_w[16];
    int t = threadIdx.x, lane = t & 63, wid = t >> 6;
    int i = blockIdx.x * 1024 + t;
    int v = (i < N_NODES) ? deg[i] : 0;
    int x = v;
    #pragma unroll
    for (int off = 1; off < 64; off <<= 1) {
        int y = __shfl_up(x, off);
        if (lane >= off) x += y;
    }
    if (lane == 63) s_w[wid] = x;
    __syncthreads();
    if (t < 16) {
        int y = s_w[t];
        #pragma unroll
        for (int off = 1; off < 16; off <<= 1) {
            int z = __shfl_up(y, off);
            if (t >= off) y += z;
        }
        s_w[t] = y;
    }
    __syncthreads();
    int woff = wid ? s_w[wid - 1] : 0;
    if (i < N_NODES) rowp[i] = woff + x - v;         // exclusive within chunk
    if (t == 1023) bsum[blockIdx.x] = s_w[15];
}

__global__ void scan2_k(const int* __restrict__ bsum, int* __restrict__ boff,
                        int* __restrict__ rowp) {
    int t = threadIdx.x;                              // 64 threads
    int v = (t < SCAN_B) ? bsum[t] : 0;
    int x = v;
    #pragma unroll
    for (int off = 1; off < 64; off <<= 1) {
        int y = __shfl_up(x, off);
        if (t >= off) x += y;
    }
    if (t < SCAN_B) boff[t] = x - v;                  // exclusive
    if (t == SCAN_B - 1) rowp[N_NODES] = x;           // total = E
}

__global__ void scan3_k(int* __restrict__ rowp, const int* __restrict__ boff) {
    int i = blockIdx.x * 1024 + threadIdx.x;
    if (i < N_NODES) rowp[i] += boff[blockIdx.x];
}

__global__ void fill_k(const int* __restrict__ src, const int* __restrict__ dst,
                       const int* __restrict__ rowp, const int* __restrict__ pos,
                       int* __restrict__ csr) {
    int e = blockIdx.x * 256 + threadIdx.x;
    if (e < N_EDGES) csr[rowp[dst[e]] + pos[e]] = src[e];
}

// graph_ids are sorted -> per-graph count via two binary searches, no atomics
__global__ void gcnt_bsearch_k(const int* __restrict__ gids, int* __restrict__ gcnt) {
    int g = threadIdx.x;                              // 128 threads, 1 block
    if (g >= NG) return;
    int lo = 0, hi = N_NODES;
    while (lo < hi) { int mid = (lo + hi) >> 1; if (gids[mid] < g) lo = mid + 1; else hi = mid; }
    int b = lo;
    lo = b; hi = N_NODES;
    while (lo < hi) { int mid = (lo + hi) >> 1; if (gids[mid] < g + 1) lo = mid + 1; else hi = mid; }
    gcnt[g] = lo - b;
}

// ---------------------------------------------------------------------------
// Prep: feat f32 -> bf16 ; zero hc pad cols ; weights -> MFMA fragment order
// ---------------------------------------------------------------------------
__global__ void fconv_k(const float* __restrict__ in, unsigned short* __restrict__ out) {
    int i = blockIdx.x * 256 + threadIdx.x;           // one thread = 8 elems
    if (i >= N_NODES * FIN / 8) return;
    const float4* p = (const float4*)(in + (size_t)i * 8);
    float4 a = p[0], b = p[1];
    s16x8 o;
    o[0] = (short)bf16_rne(a.x); o[1] = (short)bf16_rne(a.y);
    o[2] = (short)bf16_rne(a.z); o[3] = (short)bf16_rne(a.w);
    o[4] = (short)bf16_rne(b.x); o[5] = (short)bf16_rne(b.y);
    o[6] = (short)bf16_rne(b.z); o[7] = (short)bf16_rne(b.w);
    *(s16x8*)(out + (size_t)i * 8) = o;
}

__global__ void zeropad_k(unsigned short* __restrict__ hc) {
    int i = blockIdx.x * 256 + threadIdx.x;
    if (i < N_NODES) {
        s16x8 z = {0, 0, 0, 0, 0, 0, 0, 0};
        *(s16x8*)(hc + (size_t)i * 224 + 216) = z;    // cols 216..223 = 0
    }
}

// fragment-order weights: for ks-tile, n-tile: lane l elem j =
//   W[ks*32 + (l>>4)*8 + j][nt*16 + (l&15)]  (0 outside real K x 108)
// kstile layout (global): Wemb ks 0..1, Wp1 2..5, Wn1 6..12, Wp2 13..16, Wn2 17..23
__global__ void wprep_k(const float* __restrict__ W0, const float* __restrict__ W1,
                        const float* __restrict__ W2, const float* __restrict__ W3,
                        const float* __restrict__ W4, unsigned short* __restrict__ Wf) {
    int b = blockIdx.x;                               // 0..167 = kst*7 + nt
    int kst = b / 7, nt = b % 7, lane = threadIdx.x;  // 64 threads
    const float* W; int Kr, ks;
    if (kst < 2)       { W = W0; Kr = 64;  ks = kst;      }
    else if (kst < 6)  { W = W1; Kr = 108; ks = kst - 2;  }
    else if (kst < 13) { W = W2; Kr = 216; ks = kst - 6;  }
    else if (kst < 17) { W = W3; Kr = 108; ks = kst - 13; }
    else               { W = W4; Kr = 216; ks = kst - 17; }
    int n = nt * 16 + (lane & 15);
    s16x8 o;
    #pragma unroll
    for (int j = 0; j < 8; ++j) {
        int k = ks * 32 + (lane >> 4) * 8 + j;
        float v = (k < Kr && n < HD) ? W[k * HD + n] : 0.0f;
        o[j] = (short)bf16_rne(v);
    }
    *(s16x8*)(Wf + (size_t)b * 512 + lane * 8) = o;
}

// ---------------------------------------------------------------------------
// MFMA GEMM: one wave = 16 nodes x 112 out-cols (7 tiles), K = KSTEPS*32
// EPI: 0=embed(h f32 + hc bf16)  1=pool(relu -> m bf16)
//      2=apply(norm+residual -> h f32 + hc bf16)  3=apply-final(-> gsum atomics)
// ---------------------------------------------------------------------------
template <int KSTEPS, int EPI>
__global__ __launch_bounds__(256) void gemm_k(
    const unsigned short* __restrict__ A, int strideA,
    const unsigned short* __restrict__ Wf, const float* __restrict__ bias,
    float* __restrict__ hio, unsigned short* __restrict__ obf, int strideO,
    const int* __restrict__ gids, float* __restrict__ gsum) {
    int t = threadIdx.x, lane = t & 63, wave = t >> 6;
    int wrow = (blockIdx.x * 4 + wave) * 16;
    if (wrow >= N_NODES) return;
    int l15 = lane & 15, lg = lane >> 4;

    f32x4 acc[7];
    #pragma unroll
    for (int nt = 0; nt < 7; ++nt) acc[nt] = (f32x4){0.f, 0.f, 0.f, 0.f};

    const unsigned short* arow = A + (size_t)(wrow + l15) * strideA + lg * 8;
    #pragma unroll
    for (int ks = 0; ks < KSTEPS; ++ks) {
        s16x8 a = *(const s16x8*)(arow + ks * 32);
        const unsigned short* wp = Wf + ((size_t)(ks * 7) * 64 + lane) * 8;
        #pragma unroll
        for (int nt = 0; nt < 7; ++nt) {
            s16x8 b = *(const s16x8*)(wp + (size_t)nt * 512);
            acc[nt] = __builtin_amdgcn_mfma_f32_16x16x32_bf16(a, b, acc[nt], 0, 0, 0);
        }
    }

    // D layout: col = nt*16 + l15, row = wrow + lg*4 + r
    if (EPI == 0) {                                   // embed
        #pragma unroll
        for (int nt = 0; nt < 7; ++nt) {
            int col = nt * 16 + l15;
            if (col >= HD) continue;
            float bv = bias[col];
            #pragma unroll
            for (int r = 0; r < 4; ++r) {
                int row = wrow + lg * 4 + r;
                float v = acc[nt][r] + bv;
                hio[(size_t)row * HD + col] = v;
                obf[(size_t)row * 224 + col] = bf16_rne(v);
            }
        }
    } else if (EPI == 1) {                            // pool: relu -> m bf16
        #pragma unroll
        for (int nt = 0; nt < 7; ++nt) {
            int col = nt * 16 + l15;
            float bv = (col < HD) ? bias[col] : 0.0f;
            #pragma unroll
            for (int r = 0; r < 4; ++r) {
                int row = wrow + lg * 4 + r;
                float v = fmaxf(acc[nt][r] + bv, 0.0f);
                obf[(size_t)row * strideO + col] = bf16_rne(v);
            }
        }
    } else {                                          // apply / apply-final
        float bval[7][4];
        float ss[4] = {0.f, 0.f, 0.f, 0.f};
        #pragma unroll
        for (int nt = 0; nt < 7; ++nt) {
            int col = nt * 16 + l15;
            bool valid = (col < HD);
            float bv = valid ? bias[col] : 0.0f;
            #pragma unroll
            for (int r = 0; r < 4; ++r) {
                float v = valid ? (acc[nt][r] + bv) : 0.0f;
                bval[nt][r] = v;
                ss[r] += v * v;
            }
        }
        #pragma unroll
        for (int r = 0; r < 4; ++r) {
            ss[r] += __shfl_xor(ss[r], 1);
            ss[r] += __shfl_xor(ss[r], 2);
            ss[r] += __shfl_xor(ss[r], 4);
            ss[r] += __shfl_xor(ss[r], 8);
        }
        float rn[4];
        #pragma unroll
        for (int r = 0; r < 4; ++r) rn[r] = 1.0f / fmaxf(sqrtf(ss[r]), 1e-12f);

        float hn[7][4];
        #pragma unroll
        for (int nt = 0; nt < 7; ++nt) {
            int col = nt * 16 + l15;
            bool valid = (col < HD);
            #pragma unroll
            for (int r = 0; r < 4; ++r) {
                int row = wrow + lg * 4 + r;
                float hv = valid ? hio[(size_t)row * HD + col] : 0.0f;
                hn[nt][r] = hv + fmaxf(bval[nt][r] * rn[r], 0.0f);
            }
        }
        if (EPI == 2) {
            #pragma unroll
            for (int nt = 0; nt < 7; ++nt) {
                int col = nt * 16 + l15;
                if (col >= HD) continue;
                #pragma unroll
                for (int r = 0; r < 4; ++r) {
                    int row = wrow + lg * 4 + r;
                    hio[(size_t)row * HD + col] = hn[nt][r];
                    obf[(size_t)row * 224 + col] = bf16_rne(hn[nt][r]);
                }
            }
        } else {                                      // EPI == 3: graph-mean accum
            int g0 = gids[wrow], g15 = gids[wrow + 15];
            if (g0 == g15) {
                #pragma unroll
                for (int nt = 0; nt < 7; ++nt) {
                    int col = nt * 16 + l15;
                    float cs = hn[nt][0] + hn[nt][1] + hn[nt][2] + hn[nt][3];
                    cs += __shfl_xor(cs, 16);
                    cs += __shfl_xor(cs, 32);
                    if (lane < 16 && col < HD) atomicAdd(&gsum[g0 * HD + col], cs);
                }
            } else {
                int gr[4];
                #pragma unroll
                for (int r = 0; r < 4; ++r) gr[r] = gids[wrow + lg * 4 + r];
                #pragma unroll
                for (int nt = 0; nt < 7; ++nt) {
                    int col = nt * 16 + l15;
                    if (col >= HD) continue;
                    #pragma unroll
                    for (int r = 0; r < 4; ++r)
                        atomicAdd(&gsum[gr[r] * HD + col], hn[nt][r]);
                }
            }
        }
    }
}

// ---------------------------------------------------------------------------
// Aggregation: c[v] = mean over incoming edges of m_bf[src]; write bf16
// into hc cols 108..215. One wave per node, lanes 0..53 own 2 cols each.
// ---------------------------------------------------------------------------
__global__ void aggregate_k(const unsigned short* __restrict__ m,
                            const int* __restrict__ rowp, const int* __restrict__ csr,
                            unsigned short* __restrict__ hc) {
    int v = blockIdx.x, t = threadIdx.x;
    int beg = rowp[v], end = rowp[v + 1];
    float s0 = 0.f, s1 = 0.f;
    if (t < 54) {
        int i = beg;
        for (; i + 1 < end; i += 2) {
            int sv0 = csr[i], sv1 = csr[i + 1];
            unsigned u0 = *(const unsigned*)(m + (size_t)sv0 * 112 + 2 * t);
            unsigned u1 = *(const unsigned*)(m + (size_t)sv1 * 112 + 2 * t);
            s0 += bf16_to_f(u0 & 0xFFFFu) + bf16_to_f(u1 & 0xFFFFu);
            s1 += bf16_to_f(u0 >> 16) + bf16_to_f(u1 >> 16);
        }
        if (i < end) {
            int sv = csr[i];
            unsigned u = *(const unsigned*)(m + (size_t)sv * 112 + 2 * t);
            s0 += bf16_to_f(u & 0xFFFFu);
            s1 += bf16_to_f(u >> 16);
        }
        float inv = (end > beg) ? 1.0f / (float)(end - beg) : 0.0f;
        unsigned pk = (unsigned)bf16_rne(s0 * inv) | ((unsigned)bf16_rne(s1 * inv) << 16);
        *(unsigned*)(hc + (size_t)v * 224 + 108 + 2 * t) = pk;
    }
}

__global__ void finalize_k(const float* __restrict__ gsum, const int* __restrict__ gcnt,
                           float* __restrict__ out) {
    int i = blockIdx.x * 256 + threadIdx.x;
    if (i < NG * HD) {
        int g = i / HD;
        int cnt = gcnt[g];
        float inv = (cnt > 0) ? 1.0f / (float)cnt : 0.0f;
        out[i] = gsum[i] * inv;
    }
}

// ---------------------------------------------------------------------------
extern "C" void kernel_launch(void* const* d_in, const int* in_sizes, int n_in,
                              void* d_out, int out_size, void* d_ws, size_t ws_size,
                              hipStream_t stream) {
    const float* feat = (const float*)d_in[0];
    const int* src  = (const int*)d_in[4];
    const int* dst  = (const int*)d_in[5];
    const int* gids = (const int*)d_in[6];
    const float* Wemb = (const float*)d_in[7];
    const float* bemb = (const float*)d_in[8];
    const float* Wp1  = (const float*)d_in[9];
    const float* bp1  = (const float*)d_in[10];
    const float* Wn1  = (const float*)d_in[11];
    const float* bn1  = (const float*)d_in[12];
    const float* Wp2  = (const float*)d_in[13];
    const float* bp2  = (const float*)d_in[14];
    const float* Wn2  = (const float*)d_in[15];
    const float* bn2  = (const float*)d_in[16];
    float* out = (float*)d_out;
    (void)in_sizes; (void)n_in; (void)out_size; (void)ws_size;

    char* ws = (char*)d_ws;
    size_t off = 0;
    auto carve = [&](size_t bytes) -> char* {
        char* p = ws + off;
        off = (off + bytes + 255) & ~(size_t)255;
        return p;
    };
    float*          h_f32 = (float*)carve((size_t)N_NODES * HD * 4);
    unsigned short* hc    = (unsigned short*)carve((size_t)N_NODES * 224 * 2);
    unsigned short* m_bf  = (unsigned short*)carve((size_t)N_NODES * 112 * 2);
    unsigned short* fbf   = (unsigned short*)carve((size_t)N_NODES * FIN * 2);
    unsigned short* Wf    = (unsigned short*)carve((size_t)24 * 7 * 512 * 2);
    int* deg  = (int*)carve((size_t)N_NODES * 4);
    int* rowp = (int*)carve((size_t)(N_NODES + 1) * 4);
    int* pos  = (int*)carve((size_t)N_EDGES * 4);
    int* csr  = (int*)carve((size_t)N_EDGES * 4);
    int* bsum = (int*)carve((size_t)SCAN_B * 4);
    int* boff = (int*)carve((size_t)SCAN_B * 4);
    float* gsum = (float*)carve((size_t)NG * HD * 4);
    int*   gcnt = (int*)carve((size_t)NG * 4);

    hipMemsetAsync(deg,  0, (size_t)N_NODES * 4, stream);
    hipMemsetAsync(gsum, 0, (size_t)NG * HD * 4, stream);

    // CSR + graph counts (gids sorted -> binary search, no atomics)
    count_k<<<(N_EDGES + 255) / 256, 256, 0, stream>>>(dst, deg, pos);
    scan1_k<<<SCAN_B, 1024, 0, stream>>>(deg, rowp, bsum);
    scan2_k<<<1, 64, 0, stream>>>(bsum, boff, rowp);
    scan3_k<<<SCAN_B, 1024, 0, stream>>>(rowp, boff);
    fill_k<<<(N_EDGES + 255) / 256, 256, 0, stream>>>(src, dst, rowp, pos, csr);
    gcnt_bsearch_k<<<1, NG, 0, stream>>>(gids, gcnt);

    // prep
    fconv_k<<<(N_NODES * FIN / 8 + 255) / 256, 256, 0, stream>>>(feat, fbf);
    zeropad_k<<<(N_NODES + 255) / 256, 256, 0, stream>>>(hc);
    wprep_k<<<168, 64, 0, stream>>>(Wemb, Wp1, Wn1, Wp2, Wn2, Wf);

    const int GB = (N_NODES / 16 + 3) / 4;           // 782 blocks, 4 waves each
    unsigned short* Wf_emb = Wf + (size_t)0  * 7 * 512;
    unsigned short* Wf_p1  = Wf + (size_t)2  * 7 * 512;
    unsigned short* Wf_n1  = Wf + (size_t)6  * 7 * 512;
    unsigned short* Wf_p2  = Wf + (size_t)13 * 7 * 512;
    unsigned short* Wf_n2  = Wf + (size_t)17 * 7 * 512;

    // layer 0: embed
    gemm_k<2, 0><<<GB, 256, 0, stream>>>(fbf, FIN, Wf_emb, bemb, h_f32, hc, 224, nullptr, nullptr);
    // layer 1
    gemm_k<4, 1><<<GB, 256, 0, stream>>>(hc, 224, Wf_p1, bp1, nullptr, m_bf, 112, nullptr, nullptr);
    aggregate_k<<<N_NODES, 64, 0, stream>>>(m_bf, rowp, csr, hc);
    gemm_k<7, 2><<<GB, 256, 0, stream>>>(hc, 224, Wf_n1, bn1, h_f32, hc, 224, nullptr, nullptr);
    // layer 2
    gemm_k<4, 1><<<GB, 256, 0, stream>>>(hc, 224, Wf_p2, bp2, nullptr, m_bf, 112, nullptr, nullptr);
    aggregate_k<<<N_NODES, 64, 0, stream>>>(m_bf, rowp, csr, hc);
    gemm_k<7, 3><<<GB, 256, 0, stream>>>(hc, 224, Wf_n2, bn2, h_f32, nullptr, 0, gids, gsum);

    finalize_k<<<(NG * HD + 255) / 256, 256, 0, stream>>>(gsum, gcnt, out);
}

// Round 4
// 194.417 us; speedup vs baseline: 3.5277x; 1.1614x over previous
//
#include <hip/hip_runtime.h>

#define N_NODES 50000
#define N_EDGES 800000
#define NG      128
#define FIN     64
#define HD      108
#define SCAN_B  49          // ceil(50000/1024)

typedef __attribute__((ext_vector_type(8))) short s16x8;   // 8 bf16 = 4 VGPRs
typedef __attribute__((ext_vector_type(4))) float f32x4;

__device__ __forceinline__ unsigned short bf16_rne(float x) {
    unsigned u = __float_as_uint(x);
    u += 0x7FFFu + ((u >> 16) & 1u);
    return (unsigned short)(u >> 16);
}
__device__ __forceinline__ float bf16_to_f(unsigned u16) {
    return __uint_as_float(u16 << 16);
}

// ---------------------------------------------------------------------------
// Fused prep: fconv | hc pad zero | weight repack | deg zero | gsum zero | gcnt
// block ranges: [0,1563) fconv, [1563,1759) zeropad, [1759,1801) wprep,
//               [1801,1850) deg, [1850,1864) gsum, [1864] gcnt
// ---------------------------------------------------------------------------
__global__ void prep_k(const float* __restrict__ feat, unsigned short* __restrict__ fbf,
                       unsigned short* __restrict__ hc,
                       const float* __restrict__ W0, const float* __restrict__ W1,
                       const float* __restrict__ W2, const float* __restrict__ W3,
                       const float* __restrict__ W4, unsigned short* __restrict__ Wf,
                       int* __restrict__ deg, float* __restrict__ gsum,
                       const int* __restrict__ gids, int* __restrict__ gcnt) {
    int b = blockIdx.x, t = threadIdx.x;
    if (b < 1563) {                                   // feat f32 -> bf16, 8/thread
        int i = b * 256 + t;
        if (i < N_NODES * FIN / 8) {
            const float4* p = (const float4*)(feat + (size_t)i * 8);
            float4 a = p[0], c = p[1];
            s16x8 o;
            o[0] = (short)bf16_rne(a.x); o[1] = (short)bf16_rne(a.y);
            o[2] = (short)bf16_rne(a.z); o[3] = (short)bf16_rne(a.w);
            o[4] = (short)bf16_rne(c.x); o[5] = (short)bf16_rne(c.y);
            o[6] = (short)bf16_rne(c.z); o[7] = (short)bf16_rne(c.w);
            *(s16x8*)(fbf + (size_t)i * 8) = o;
        }
    } else if (b < 1759) {                            // hc cols 216..223 = 0
        int i = (b - 1563) * 256 + t;
        if (i < N_NODES) {
            s16x8 z = {0, 0, 0, 0, 0, 0, 0, 0};
            *(s16x8*)(hc + (size_t)i * 224 + 216) = z;
        }
    } else if (b < 1801) {                            // weight repack, 1 tile/wave
        int tile = (b - 1759) * 4 + (t >> 6), lane = t & 63;
        if (tile < 168) {
            int kst = tile / 7, nt = tile % 7;
            const float* W; int Kr, ks;
            if (kst < 2)       { W = W0; Kr = 64;  ks = kst;      }
            else if (kst < 6)  { W = W1; Kr = 108; ks = kst - 2;  }
            else if (kst < 13) { W = W2; Kr = 216; ks = kst - 6;  }
            else if (kst < 17) { W = W3; Kr = 108; ks = kst - 13; }
            else               { W = W4; Kr = 216; ks = kst - 17; }
            int n = nt * 16 + (lane & 15);
            s16x8 o;
            #pragma unroll
            for (int j = 0; j < 8; ++j) {
                int k = ks * 32 + (lane >> 4) * 8 + j;
                float v = (k < Kr && n < HD) ? W[k * HD + n] : 0.0f;
                o[j] = (short)bf16_rne(v);
            }
            *(s16x8*)(Wf + (size_t)tile * 512 + lane * 8) = o;
        }
    } else if (b < 1850) {                            // deg = 0 (int4)
        int i = (b - 1801) * 256 + t;
        if (i < N_NODES / 4) ((int4*)deg)[i] = (int4){0, 0, 0, 0};
    } else if (b < 1864) {                            // gsum = 0 (int4)
        int i = (b - 1850) * 256 + t;
        if (i < NG * HD / 4) ((int4*)gsum)[i] = (int4){0, 0, 0, 0};
    } else {                                          // per-graph counts (sorted)
        int g = t;
        if (g < NG) {
            int lo = 0, hi = N_NODES;
            while (lo < hi) { int mid = (lo + hi) >> 1; if (gids[mid] < g) lo = mid + 1; else hi = mid; }
            int s = lo;
            lo = s; hi = N_NODES;
            while (lo < hi) { int mid = (lo + hi) >> 1; if (gids[mid] < g + 1) lo = mid + 1; else hi = mid; }
            gcnt[g] = lo - s;
        }
    }
}

// ---------------------------------------------------------------------------
// CSR construction
// ---------------------------------------------------------------------------
__global__ void count_k(const int* __restrict__ dst, int* __restrict__ deg,
                        int* __restrict__ pos) {
    int e = blockIdx.x * 256 + threadIdx.x;
    if (e < N_EDGES) pos[e] = atomicAdd(&deg[dst[e]], 1);
}

__global__ void scan1_k(const int* __restrict__ deg, int* __restrict__ rowp,
                        int* __restrict__ bsum) {
    __shared__ int s_w[16];
    int t = threadIdx.x, lane = t & 63, wid = t >> 6;
    int i = blockIdx.x * 1024 + t;
    int v = (i < N_NODES) ? deg[i] : 0;
    int x = v;
    #pragma unroll
    for (int off = 1; off < 64; off <<= 1) {
        int y = __shfl_up(x, off);
        if (lane >= off) x += y;
    }
    if (lane == 63) s_w[wid] = x;
    __syncthreads();
    if (t < 16) {
        int y = s_w[t];
        #pragma unroll
        for (int off = 1; off < 16; off <<= 1) {
            int z = __shfl_up(y, off);
            if (t >= off) y += z;
        }
        s_w[t] = y;
    }
    __syncthreads();
    int woff = wid ? s_w[wid - 1] : 0;
    if (i < N_NODES) rowp[i] = woff + x - v;
    if (t == 1023) bsum[blockIdx.x] = s_w[15];
}

__global__ void scan2_k(const int* __restrict__ bsum, int* __restrict__ boff,
                        int* __restrict__ rowp) {
    int t = threadIdx.x;
    int v = (t < SCAN_B) ? bsum[t] : 0;
    int x = v;
    #pragma unroll
    for (int off = 1; off < 64; off <<= 1) {
        int y = __shfl_up(x, off);
        if (t >= off) x += y;
    }
    if (t < SCAN_B) boff[t] = x - v;
    if (t == SCAN_B - 1) rowp[N_NODES] = x;
}

__global__ void scan3_k(int* __restrict__ rowp, const int* __restrict__ boff) {
    int i = blockIdx.x * 1024 + threadIdx.x;
    if (i < N_NODES) rowp[i] += boff[blockIdx.x];
}

__global__ void fill_k(const int* __restrict__ src, const int* __restrict__ dst,
                       const int* __restrict__ rowp, const int* __restrict__ pos,
                       int* __restrict__ csr) {
    int e = blockIdx.x * 256 + threadIdx.x;
    if (e < N_EDGES) csr[rowp[dst[e]] + pos[e]] = src[e];
}

// ---------------------------------------------------------------------------
// Fused GEMM. One wave = 16 nodes x 112 cols. EPI: 0=embed+pool, 2=apply+pool,
// 3=apply-final(graph-sum atomics). Pool stage reads h from a per-wave LDS
// transpose (16x136 bf16, 272B stride -> 2-way banked = free).
// ---------------------------------------------------------------------------
template <int KSTEPS, int EPI>
__global__ __launch_bounds__(256) void gemm_k(
    const unsigned short* __restrict__ A, int strideA,
    const unsigned short* __restrict__ Wf, const float* __restrict__ bias,
    const unsigned short* __restrict__ Wfp, const float* __restrict__ biasp,
    unsigned short* __restrict__ hc, unsigned short* __restrict__ m_bf,
    const int* __restrict__ gids, float* __restrict__ gsum) {
    __shared__ unsigned short s_t[4][16][136];
    int t = threadIdx.x, lane = t & 63, wave = t >> 6;
    int wrow = (blockIdx.x * 4 + wave) * 16;
    if (wrow >= N_NODES) return;
    int l15 = lane & 15, lg = lane >> 4;

    f32x4 acc[7];
    #pragma unroll
    for (int nt = 0; nt < 7; ++nt) acc[nt] = (f32x4){0.f, 0.f, 0.f, 0.f};

    const unsigned short* arow = A + (size_t)(wrow + l15) * strideA + lg * 8;
    #pragma unroll
    for (int ks = 0; ks < KSTEPS; ++ks) {
        s16x8 a = *(const s16x8*)(arow + ks * 32);
        const unsigned short* wp = Wf + ((size_t)(ks * 7) * 64 + lane) * 8;
        #pragma unroll
        for (int nt = 0; nt < 7; ++nt) {
            s16x8 bfr = *(const s16x8*)(wp + (size_t)nt * 512);
            acc[nt] = __builtin_amdgcn_mfma_f32_16x16x32_bf16(a, bfr, acc[nt], 0, 0, 0);
        }
    }

    // D layout: col = nt*16 + l15, row(local) = lg*4 + r
    float vals[7][4];
    if (EPI == 0) {                                   // embed: + bias
        #pragma unroll
        for (int nt = 0; nt < 7; ++nt) {
            int col = nt * 16 + l15;
            float bv = (col < HD) ? bias[col] : 0.0f;
            #pragma unroll
            for (int r = 0; r < 4; ++r) vals[nt][r] = acc[nt][r] + bv;
        }
    } else {                                          // apply: norm + residual
        float ss[4] = {0.f, 0.f, 0.f, 0.f};
        #pragma unroll
        for (int nt = 0; nt < 7; ++nt) {
            int col = nt * 16 + l15;
            bool valid = (col < HD);
            float bv = valid ? bias[col] : 0.0f;
            #pragma unroll
            for (int r = 0; r < 4; ++r) {
                float v = valid ? (acc[nt][r] + bv) : 0.0f;
                vals[nt][r] = v;
                ss[r] += v * v;
            }
        }
        #pragma unroll
        for (int r = 0; r < 4; ++r) {
            ss[r] += __shfl_xor(ss[r], 1);
            ss[r] += __shfl_xor(ss[r], 2);
            ss[r] += __shfl_xor(ss[r], 4);
            ss[r] += __shfl_xor(ss[r], 8);
        }
        float rn[4];
        #pragma unroll
        for (int r = 0; r < 4; ++r) rn[r] = 1.0f / fmaxf(sqrtf(ss[r]), 1e-12f);
        #pragma unroll
        for (int nt = 0; nt < 7; ++nt) {
            int col = nt * 16 + l15;
            bool valid = (col < HD);
            #pragma unroll
            for (int r = 0; r < 4; ++r) {
                int row = wrow + lg * 4 + r;
                float hv = valid ? bf16_to_f(hc[(size_t)row * 224 + col]) : 0.0f;
                vals[nt][r] = hv + fmaxf(vals[nt][r] * rn[r], 0.0f);
            }
        }
    }

    if (EPI == 3) {                                   // graph-mean accumulation
        int g0 = gids[wrow], g15 = gids[wrow + 15];
        if (g0 == g15) {
            #pragma unroll
            for (int nt = 0; nt < 7; ++nt) {
                int col = nt * 16 + l15;
                float cs = vals[nt][0] + vals[nt][1] + vals[nt][2] + vals[nt][3];
                cs += __shfl_xor(cs, 16);
                cs += __shfl_xor(cs, 32);
                if (lane < 16 && col < HD) atomicAdd(&gsum[g0 * HD + col], cs);
            }
        } else {
            int gr[4];
            #pragma unroll
            for (int r = 0; r < 4; ++r) gr[r] = gids[wrow + lg * 4 + r];
            #pragma unroll
            for (int nt = 0; nt < 7; ++nt) {
                int col = nt * 16 + l15;
                if (col >= HD) continue;
                #pragma unroll
                for (int r = 0; r < 4; ++r)
                    atomicAdd(&gsum[gr[r] * HD + col], vals[nt][r]);
            }
        }
        return;
    }

    // write h (bf16) to hc cols 0..107 and stage into LDS for the pool GEMM
    #pragma unroll
    for (int nt = 0; nt < 7; ++nt) {
        int col = nt * 16 + l15;
        #pragma unroll
        for (int r = 0; r < 4; ++r) {
            unsigned short hb = bf16_rne(vals[nt][r]);
            int lrow = lg * 4 + r;
            if (col < HD) hc[(size_t)(wrow + lrow) * 224 + col] = hb;
            s_t[wave][lrow][col] = (col < HD) ? hb : 0;
        }
    }
    // zero LDS cols 108..127 (pool reads k<128; zero-weight cols must not be NaN)
    for (int z = lane; z < 160; z += 64) {            // 16 rows x 10 dword-pairs
        int row = z / 10, dc = z % 10;
        *(unsigned*)&s_t[wave][row][108 + dc * 2] = 0u;
    }

    // pool: m = relu(h @ Wp + bp), A-fragments from LDS transpose
    f32x4 accp[7];
    #pragma unroll
    for (int nt = 0; nt < 7; ++nt) accp[nt] = (f32x4){0.f, 0.f, 0.f, 0.f};
    #pragma unroll
    for (int ks = 0; ks < 4; ++ks) {
        s16x8 a = *(const s16x8*)&s_t[wave][l15][ks * 32 + lg * 8];
        const unsigned short* wp = Wfp + ((size_t)(ks * 7) * 64 + lane) * 8;
        #pragma unroll
        for (int nt = 0; nt < 7; ++nt) {
            s16x8 bfr = *(const s16x8*)(wp + (size_t)nt * 512);
            accp[nt] = __builtin_amdgcn_mfma_f32_16x16x32_bf16(a, bfr, accp[nt], 0, 0, 0);
        }
    }
    #pragma unroll
    for (int nt = 0; nt < 7; ++nt) {
        int col = nt * 16 + l15;
        float bv = (col < HD) ? biasp[col] : 0.0f;
        #pragma unroll
        for (int r = 0; r < 4; ++r) {
            int row = wrow + lg * 4 + r;
            m_bf[(size_t)row * 112 + col] = bf16_rne(fmaxf(accp[nt][r] + bv, 0.0f));
        }
    }
}

// ---------------------------------------------------------------------------
// Aggregation: c[v] = mean over incoming edges of m_bf[src] -> hc cols 108..215
// ---------------------------------------------------------------------------
__global__ void aggregate_k(const unsigned short* __restrict__ m,
                            const int* __restrict__ rowp, const int* __restrict__ csr,
                            unsigned short* __restrict__ hc) {
    int v = blockIdx.x, t = threadIdx.x;
    int beg = rowp[v], end = rowp[v + 1];
    float s0 = 0.f, s1 = 0.f;
    if (t < 54) {
        int i = beg;
        for (; i + 1 < end; i += 2) {
            int sv0 = csr[i], sv1 = csr[i + 1];
            unsigned u0 = *(const unsigned*)(m + (size_t)sv0 * 112 + 2 * t);
            unsigned u1 = *(const unsigned*)(m + (size_t)sv1 * 112 + 2 * t);
            s0 += bf16_to_f(u0 & 0xFFFFu) + bf16_to_f(u1 & 0xFFFFu);
            s1 += bf16_to_f(u0 >> 16) + bf16_to_f(u1 >> 16);
        }
        if (i < end) {
            int sv = csr[i];
            unsigned u = *(const unsigned*)(m + (size_t)sv * 112 + 2 * t);
            s0 += bf16_to_f(u & 0xFFFFu);
            s1 += bf16_to_f(u >> 16);
        }
        float inv = (end > beg) ? 1.0f / (float)(end - beg) : 0.0f;
        unsigned pk = (unsigned)bf16_rne(s0 * inv) | ((unsigned)bf16_rne(s1 * inv) << 16);
        *(unsigned*)(hc + (size_t)v * 224 + 108 + 2 * t) = pk;
    }
}

__global__ void finalize_k(const float* __restrict__ gsum, const int* __restrict__ gcnt,
                           float* __restrict__ out) {
    int i = blockIdx.x * 256 + threadIdx.x;
    if (i < NG * HD) {
        int g = i / HD;
        int cnt = gcnt[g];
        float inv = (cnt > 0) ? 1.0f / (float)cnt : 0.0f;
        out[i] = gsum[i] * inv;
    }
}

// ---------------------------------------------------------------------------
extern "C" void kernel_launch(void* const* d_in, const int* in_sizes, int n_in,
                              void* d_out, int out_size, void* d_ws, size_t ws_size,
                              hipStream_t stream) {
    const float* feat = (const float*)d_in[0];
    const int* src  = (const int*)d_in[4];
    const int* dst  = (const int*)d_in[5];
    const int* gids = (const int*)d_in[6];
    const float* Wemb = (const float*)d_in[7];
    const float* bemb = (const float*)d_in[8];
    const float* Wp1  = (const float*)d_in[9];
    const float* bp1  = (const float*)d_in[10];
    const float* Wn1  = (const float*)d_in[11];
    const float* bn1  = (const float*)d_in[12];
    const float* Wp2  = (const float*)d_in[13];
    const float* bp2  = (const float*)d_in[14];
    const float* Wn2  = (const float*)d_in[15];
    const float* bn2  = (const float*)d_in[16];
    float* out = (float*)d_out;
    (void)in_sizes; (void)n_in; (void)out_size; (void)ws_size;

    char* ws = (char*)d_ws;
    size_t off = 0;
    auto carve = [&](size_t bytes) -> char* {
        char* p = ws + off;
        off = (off + bytes + 255) & ~(size_t)255;
        return p;
    };
    unsigned short* hc    = (unsigned short*)carve((size_t)N_NODES * 224 * 2);
    unsigned short* m_bf  = (unsigned short*)carve((size_t)N_NODES * 112 * 2);
    unsigned short* fbf   = (unsigned short*)carve((size_t)N_NODES * FIN * 2);
    unsigned short* Wf    = (unsigned short*)carve((size_t)24 * 7 * 512 * 2);
    int* deg  = (int*)carve((size_t)N_NODES * 4);
    int* rowp = (int*)carve((size_t)(N_NODES + 1) * 4);
    int* pos  = (int*)carve((size_t)N_EDGES * 4);
    int* csr  = (int*)carve((size_t)N_EDGES * 4);
    int* bsum = (int*)carve((size_t)SCAN_B * 4);
    int* boff = (int*)carve((size_t)SCAN_B * 4);
    float* gsum = (float*)carve((size_t)NG * HD * 4);
    int*   gcnt = (int*)carve((size_t)NG * 4);

    // fused prep: fconv + hc-pad + weight repack + deg/gsum zero + gcnt
    prep_k<<<1865, 256, 0, stream>>>(feat, fbf, hc, Wemb, Wp1, Wn1, Wp2, Wn2, Wf,
                                     deg, gsum, gids, gcnt);

    count_k<<<(N_EDGES + 255) / 256, 256, 0, stream>>>(dst, deg, pos);
    scan1_k<<<SCAN_B, 1024, 0, stream>>>(deg, rowp, bsum);
    scan2_k<<<1, 64, 0, stream>>>(bsum, boff, rowp);
    scan3_k<<<SCAN_B, 1024, 0, stream>>>(rowp, boff);
    fill_k<<<(N_EDGES + 255) / 256, 256, 0, stream>>>(src, dst, rowp, pos, csr);

    const int GB = (N_NODES / 16 + 3) / 4;           // 782 blocks x 4 waves
    unsigned short* Wf_emb = Wf + (size_t)0  * 7 * 512;
    unsigned short* Wf_p1  = Wf + (size_t)2  * 7 * 512;
    unsigned short* Wf_n1  = Wf + (size_t)6  * 7 * 512;
    unsigned short* Wf_p2  = Wf + (size_t)13 * 7 * 512;
    unsigned short* Wf_n2  = Wf + (size_t)17 * 7 * 512;

    // layer 0+1a: embed + pool1 (fused)
    gemm_k<2, 0><<<GB, 256, 0, stream>>>(fbf, FIN, Wf_emb, bemb, Wf_p1, bp1,
                                         hc, m_bf, nullptr, nullptr);
    aggregate_k<<<N_NODES, 64, 0, stream>>>(m_bf, rowp, csr, hc);
    // layer 1b+2a: apply1 + pool2 (fused)
    gemm_k<7, 2><<<GB, 256, 0, stream>>>(hc, 224, Wf_n1, bn1, Wf_p2, bp2,
                                         hc, m_bf, nullptr, nullptr);
    aggregate_k<<<N_NODES, 64, 0, stream>>>(m_bf, rowp, csr, hc);
    // layer 2b: apply2 -> graph sums
    gemm_k<7, 3><<<GB, 256, 0, stream>>>(hc, 224, Wf_n2, bn2, nullptr, nullptr,
                                         hc, nullptr, gids, gsum);

    finalize_k<<<(NG * HD + 255) / 256, 256, 0, stream>>>(gsum, gcnt, out);
}